// Round 2
// baseline (347.685 us; speedup 1.0000x reference)
//
#include <hip/hip_runtime.h>

#define RR 4
#define NS 17
#define BB 4
#define CC 128
#define HH 96
#define WW 160
#define HWSZ (HH * WW)

// Block: (8,32) = 256 threads. Thread = 1 row x 4 cols pixel quad.
// Block pixel tile: 32x32. LDS tgt tile: 40x40 (halo RR each side).
#define TW 32
#define THT 32
#define TCOLS (TW + 2 * RR)    // 40
#define TROWS (THT + 2 * RR)   // 40
#define NF4 (TROWS * TCOLS / 4)  // 400 float4 per channel tile
#define CCHUNK 8
#define NCHUNK (CC / CCHUNK)   // 16
#define F4STRIDE (HWSZ / 4)    // 3840 float4 per channel plane

typedef float4 f4;

__global__ __launch_bounds__(256, 3)
void cost_volume_kernel(const float* __restrict__ src,
                        const float* __restrict__ tgt,
                        float* __restrict__ out) {
    __shared__ __align__(16) float tile[TROWS][TCOLS];  // 6400 B

    const int x   = threadIdx.x;           // 0..7  (w-quad)
    const int ty  = threadIdx.y;           // 0..31 (pixel row)
    const int tid = ty * 8 + x;            // 0..255

    const int w0 = blockIdx.x * TW;        // {0,32,64,96,128}
    const int h0 = blockIdx.y * THT;       // {0,32,64}
    const int b  = blockIdx.z & 3;
    const int c0 = (blockIdx.z >> 2) * CCHUNK;

    const float* tgt_b = tgt + (size_t)(b * CC) * HWSZ;
    const float* src_b = src + (size_t)(b * CC) * HWSZ;

    // ---- precompute staging slots (channel-invariant) ----
    // slot A: float4 #tid, slot B: float4 #(tid+256) (valid if < 400)
    const int idxA = tid, idxB = tid + 256;
    const int rA = idxA / 10, sA = idxA - 10 * rA;   // 10 float4 per tile row
    const int rB = idxB / 10, sB = idxB - 10 * rB;
    const int grA = h0 - RR + rA, gcA = w0 - RR + 4 * sA;
    const int grB = h0 - RR + rB, gcB = w0 - RR + 4 * sB;
    // float4s are all-or-nothing OOB (halo = 4 = float4 width)
    const bool vA = (grA >= 0) && (grA < HH) && (gcA >= 0) && (gcA <= WW - 4);
    const bool vB = (idxB < NF4) && (grB >= 0) && (grB < HH) && (gcB >= 0) && (gcB <= WW - 4);
    const f4* gA = (const f4*)(tgt_b + ((size_t)c0 * HWSZ + grA * WW + gcA));
    const f4* gB = (const f4*)(tgt_b + ((size_t)c0 * HWSZ + grB * WW + gcB));
    const f4* gS = (const f4*)(src_b + ((size_t)c0 * HWSZ + (h0 + ty) * WW + w0 + 4 * x));

    const f4 zero4 = make_float4(0.f, 0.f, 0.f, 0.f);

    float acc[NS][4];
#pragma unroll
    for (int s = 0; s < NS; ++s)
#pragma unroll
        for (int j = 0; j < 4; ++j) acc[s][j] = 0.f;

    // prologue prefetch (channel c0)
    f4 pA = vA ? gA[0] : zero4;
    f4 pB = vB ? gB[0] : zero4;
    f4 pS = gS[0];

    for (int cc = 0; cc < CCHUNK; ++cc) {
        // stage to LDS
        ((f4*)tile)[idxA] = pA;
        if (idxB < NF4) ((f4*)tile)[idxB] = pB;
        float sv[4] = {pS.x, pS.y, pS.z, pS.w};
        __syncthreads();

        // prefetch next channel while computing this one
        if (cc + 1 < CCHUNK) {
            const size_t o = (size_t)(cc + 1) * F4STRIDE;
            pA = vA ? gA[o] : zero4;
            pB = vB ? gB[o] : zero4;
            pS = gS[o];
        }

        const int rr = RR + ty;      // pixel row in tile
        const int cb = 4 * x;        // leftmost col of 12-wide row segment

        // row segment: cols cb .. cb+11  (pixel cols are cb+4..cb+7)
        f4 R0 = *(const f4*)&tile[rr][cb];
        f4 R1 = *(const f4*)&tile[rr][cb + 4];
        f4 R2 = *(const f4*)&tile[rr][cb + 8];
        float row[12] = {R0.x, R0.y, R0.z, R0.w,
                         R1.x, R1.y, R1.z, R1.w,
                         R2.x, R2.y, R2.z, R2.w};

        // s = 0: center
#pragma unroll
        for (int j = 0; j < 4; ++j) acc[0][j] = fmaf(sv[j], row[4 + j], acc[0][j]);

        // vertical offsets: s = 4i-3 (up, h-i), 4i-2 (down, h+i)
#pragma unroll
        for (int i = 1; i <= RR; ++i) {
            f4 up = *(const f4*)&tile[rr - i][cb + 4];
            f4 dn = *(const f4*)&tile[rr + i][cb + 4];
            float u[4] = {up.x, up.y, up.z, up.w};
            float d[4] = {dn.x, dn.y, dn.z, dn.w};
#pragma unroll
            for (int j = 0; j < 4; ++j) {
                acc[4 * i - 3][j] = fmaf(sv[j], u[j], acc[4 * i - 3][j]);
                acc[4 * i - 2][j] = fmaf(sv[j], d[j], acc[4 * i - 2][j]);
            }
        }

        // horizontal offsets: s = 4i-1 (left, w-i), 4i (right, w+i)
#pragma unroll
        for (int i = 1; i <= RR; ++i) {
#pragma unroll
            for (int j = 0; j < 4; ++j) {
                acc[4 * i - 1][j] = fmaf(sv[j], row[4 + j - i], acc[4 * i - 1][j]);
                acc[4 * i    ][j] = fmaf(sv[j], row[4 + j + i], acc[4 * i    ][j]);
            }
        }
        __syncthreads();
    }

    // epilogue: atomic accumulate (NCHUNK chunk-blocks race per output)
    const int h = h0 + ty;
    const int wb = w0 + 4 * x;
#pragma unroll
    for (int s = 0; s < NS; ++s) {
        float* op = out + (((size_t)(b * NS + s)) * HH + h) * WW + wb;
#pragma unroll
        for (int j = 0; j < 4; ++j) atomicAdd(op + j, acc[s][j]);
    }
}

extern "C" void kernel_launch(void* const* d_in, const int* in_sizes, int n_in,
                              void* d_out, int out_size, void* d_ws, size_t ws_size,
                              hipStream_t stream) {
    const float* src = (const float*)d_in[0];
    const float* tgt = (const float*)d_in[1];
    float* out = (float*)d_out;

    // out is poisoned 0xAA before every launch; we accumulate atomically -> zero it
    hipMemsetAsync(out, 0, (size_t)out_size * sizeof(float), stream);

    dim3 block(8, 32, 1);                        // 256 threads
    dim3 grid(WW / TW, HH / THT, BB * NCHUNK);   // (5, 3, 64) = 960 blocks
    cost_volume_kernel<<<grid, block, 0, stream>>>(src, tgt, out);
}

// Round 3
// 200.269 us; speedup vs baseline: 1.7361x; 1.7361x over previous
//
#include <hip/hip_runtime.h>

#define RR 4
#define NS 17
#define BB 4
#define CC 128
#define HH 96
#define WW 160
#define HWSZ (HH * WW)

// Block: (8,16) = 128 threads (2 waves). Thread = 1 row x 4 cols pixel quad.
// Block pixel tile: 16 rows x 32 cols. LDS tgt tile: 24 x 40 (halo RR each side).
#define TW 32
#define THT 16
#define TCOLS (TW + 2 * RR)      // 40
#define TROWS (THT + 2 * RR)     // 24
#define NF4 (TROWS * TCOLS / 4)  // 240 float4 per channel tile
#define CCHUNK 32
#define NCHUNK (CC / CCHUNK)     // 4  (4 atomic writers/output: proven cheap in R1)
#define F4STRIDE (HWSZ / 4)      // float4 per channel plane

typedef float4 f4;

__global__ __launch_bounds__(128, 2)
void cost_volume_kernel(const float* __restrict__ src,
                        const float* __restrict__ tgt,
                        float* __restrict__ out) {
    __shared__ __align__(16) float tile[TROWS][TCOLS];  // 3840 B

    const int x   = threadIdx.x;           // 0..7  (w-quad)
    const int ty  = threadIdx.y;           // 0..15 (pixel row)
    const int tid = ty * 8 + x;            // 0..127

    const int w0 = blockIdx.x * TW;        // {0,32,64,96,128}
    const int h0 = blockIdx.y * THT;       // {0,16,...,80}
    const int b  = blockIdx.z & 3;
    const int c0 = (blockIdx.z >> 2) * CCHUNK;

    const float* tgt_b = tgt + (size_t)(b * CC) * HWSZ;
    const float* src_b = src + (size_t)(b * CC) * HWSZ;

    // ---- channel-invariant staging slots ----
    // slot A: float4 #tid, slot B: float4 #(tid+128) (valid if < 240)
    const int idxA = tid, idxB = tid + 128;
    const int rA = idxA / 10, sA = idxA - 10 * rA;   // 10 float4 per tile row
    const int rB = idxB / 10, sB = idxB - 10 * rB;
    const int grA = h0 - RR + rA, gcA = w0 - RR + 4 * sA;
    const int grB = h0 - RR + rB, gcB = w0 - RR + 4 * sB;
    // halo = 4 = float4 width and w0 % 32 == 0 -> each f4 is all-in or all-out
    const bool vA = (grA >= 0) && (grA < HH) && (gcA >= 0) && (gcA <= WW - 4);
    const bool vB = (idxB < NF4) && (grB >= 0) && (grB < HH) && (gcB >= 0) && (gcB <= WW - 4);
    const f4* gA = (const f4*)(tgt_b + ((size_t)c0 * HWSZ + grA * WW + gcA));
    const f4* gB = (const f4*)(tgt_b + ((size_t)c0 * HWSZ + grB * WW + gcB));
    const f4* gS = (const f4*)(src_b + ((size_t)c0 * HWSZ + (h0 + ty) * WW + w0 + 4 * x));

    const f4 zero4 = make_float4(0.f, 0.f, 0.f, 0.f);

    float acc[NS][4];
#pragma unroll
    for (int s = 0; s < NS; ++s)
#pragma unroll
        for (int j = 0; j < 4; ++j) acc[s][j] = 0.f;

    // ---- depth-2 register pipeline ----
    f4 PA[2], PB[2], PS[2];
    PA[0] = vA ? gA[0] : zero4;
    PB[0] = vB ? gB[0] : zero4;
    PS[0] = gS[0];
    PA[1] = vA ? gA[F4STRIDE] : zero4;
    PB[1] = vB ? gB[F4STRIDE] : zero4;
    PS[1] = gS[F4STRIDE];

    for (int cc = 0; cc < CCHUNK; ++cc) {
        const int buf = cc & 1;
        // stage channel cc to LDS (vmcnt wait here is for loads issued 2 iters ago)
        ((f4*)tile)[idxA] = PA[buf];
        if (idxB < NF4) ((f4*)tile)[idxB] = PB[buf];
        f4 sq = PS[buf];
        __syncthreads();

        // issue loads for channel cc+2 (in flight across ~2 compute phases)
        if (cc + 2 < CCHUNK) {
            const size_t o = (size_t)(cc + 2) * F4STRIDE;
            PA[buf] = vA ? gA[o] : zero4;
            PB[buf] = vB ? gB[o] : zero4;
            PS[buf] = gS[o];
        }

        const float sv[4] = {sq.x, sq.y, sq.z, sq.w};
        const int rr = RR + ty;      // pixel row in tile
        const int cb = 4 * x;        // leftmost col of 12-wide row segment

        // row segment: cols cb .. cb+11 (pixel cols cb+4..cb+7)
        f4 R0 = *(const f4*)&tile[rr][cb];
        f4 R1 = *(const f4*)&tile[rr][cb + 4];
        f4 R2 = *(const f4*)&tile[rr][cb + 8];
        float row[12] = {R0.x, R0.y, R0.z, R0.w,
                         R1.x, R1.y, R1.z, R1.w,
                         R2.x, R2.y, R2.z, R2.w};

        // s = 0: center
#pragma unroll
        for (int j = 0; j < 4; ++j) acc[0][j] = fmaf(sv[j], row[4 + j], acc[0][j]);

        // vertical: s = 4i-3 (up, h-i), 4i-2 (down, h+i)
#pragma unroll
        for (int i = 1; i <= RR; ++i) {
            f4 up = *(const f4*)&tile[rr - i][cb + 4];
            f4 dn = *(const f4*)&tile[rr + i][cb + 4];
            float u[4] = {up.x, up.y, up.z, up.w};
            float d[4] = {dn.x, dn.y, dn.z, dn.w};
#pragma unroll
            for (int j = 0; j < 4; ++j) {
                acc[4 * i - 3][j] = fmaf(sv[j], u[j], acc[4 * i - 3][j]);
                acc[4 * i - 2][j] = fmaf(sv[j], d[j], acc[4 * i - 2][j]);
            }
        }

        // horizontal: s = 4i-1 (left, w-i), 4i (right, w+i)
#pragma unroll
        for (int i = 1; i <= RR; ++i) {
#pragma unroll
            for (int j = 0; j < 4; ++j) {
                acc[4 * i - 1][j] = fmaf(sv[j], row[4 + j - i], acc[4 * i - 1][j]);
                acc[4 * i    ][j] = fmaf(sv[j], row[4 + j + i], acc[4 * i    ][j]);
            }
        }
        __syncthreads();
    }

    // epilogue: atomic accumulate (4 chunk-blocks race per output — cheap, see R1)
    const int h = h0 + ty;
    const int wb = w0 + 4 * x;
#pragma unroll
    for (int s = 0; s < NS; ++s) {
        float* op = out + (((size_t)(b * NS + s)) * HH + h) * WW + wb;
#pragma unroll
        for (int j = 0; j < 4; ++j) atomicAdd(op + j, acc[s][j]);
    }
}

extern "C" void kernel_launch(void* const* d_in, const int* in_sizes, int n_in,
                              void* d_out, int out_size, void* d_ws, size_t ws_size,
                              hipStream_t stream) {
    const float* src = (const float*)d_in[0];
    const float* tgt = (const float*)d_in[1];
    float* out = (float*)d_out;

    // out is poisoned 0xAA before every launch; we accumulate atomically -> zero it
    hipMemsetAsync(out, 0, (size_t)out_size * sizeof(float), stream);

    dim3 block(8, 16, 1);                        // 128 threads, 2 waves
    dim3 grid(WW / TW, HH / THT, BB * NCHUNK);   // (5, 6, 16) = 480 blocks
    cost_volume_kernel<<<grid, block, 0, stream>>>(src, tgt, out);
}

// Round 4
// 132.194 us; speedup vs baseline: 2.6301x; 1.5150x over previous
//
#include <hip/hip_runtime.h>

#define RR 4
#define NS 17
#define BB 4
#define CC 128
#define HH 96
#define WW 160
#define HWSZ (HH * WW)

// Block: (32,8) = 256 threads (4 waves). Thread = 2 rows x 1 col.
// Px tile: 16 rows x 32 cols. LDS: G=4 channel tiles of 24x40.
#define TW 32
#define THT 16
#define TROWS 24
#define TCOLS 40
#define CH_F4 (TROWS * TCOLS / 4)  // 240 float4 per channel tile
#define G 4                        // channels staged per barrier pair
#define CCHUNK 32
#define NCHUNK (CC / CCHUNK)       // 4 atomic writers/output (R1: cheap)
#define NGROUP (CCHUNK / G)        // 8
#define NSLOT (G * CH_F4)          // 960 float4 per group

typedef float4 f4;

__global__ __launch_bounds__(256, 4)
void cost_volume_kernel(const float* __restrict__ src,
                        const float* __restrict__ tgt,
                        float* __restrict__ out) {
    __shared__ __align__(16) float tile[G][TROWS][TCOLS];  // 15360 B

    const int x   = threadIdx.x;          // 0..31 (col)
    const int ty  = threadIdx.y;          // 0..7  (row pair)
    const int tid = ty * TW + x;          // 0..255

    const int w0 = blockIdx.x * TW;
    const int h0 = blockIdx.y * THT;
    const int b  = blockIdx.z & 3;
    const int c0 = (blockIdx.z >> 2) * CCHUNK;

    const float* tgt_b = tgt + (size_t)(b * CC) * HWSZ;
    const float* src_b = src + (size_t)(b * CC) * HWSZ;

    // ---- channel-group-invariant staging geometry (4 f4 slots/thread) ----
    int  soff[4];
    bool sval[4];
#pragma unroll
    for (int k = 0; k < 4; ++k) {
        int s   = tid + k * 256;
        int ch  = s / CH_F4;               // 0..3 within group
        int idx = s - ch * CH_F4;
        int r   = idx / 10;                // 10 f4 per tile row
        int c   = idx - 10 * r;
        int gr  = h0 - RR + r;
        int gc  = w0 - RR + 4 * c;         // f4 all-in or all-out (halo=4)
        sval[k] = (s < NSLOT) && (gr >= 0) && (gr < HH) && (gc >= 0) && (gc <= WW - 4);
        soff[k] = ch * HWSZ + gr * WW + gc;
    }
    const float* srow = src_b + (h0 + 2 * ty) * WW + (w0 + x);
    const f4 zero4 = make_float4(0.f, 0.f, 0.f, 0.f);

    float acc[2][NS];
#pragma unroll
    for (int i = 0; i < 2; ++i)
#pragma unroll
        for (int s = 0; s < NS; ++s) acc[i][s] = 0.f;

    f4 P[4];
    float S[G][2];

    auto load_group = [&](int g) {
        const float* tg = tgt_b + (size_t)(c0 + g * G) * HWSZ;
#pragma unroll
        for (int k = 0; k < 4; ++k)
            P[k] = sval[k] ? *(const f4*)(tg + soff[k]) : zero4;
        const float* sg = srow + (size_t)(c0 + g * G) * HWSZ;
#pragma unroll
        for (int ch = 0; ch < G; ++ch) {
            S[ch][0] = sg[(size_t)ch * HWSZ];
            S[ch][1] = sg[(size_t)ch * HWSZ + WW];
        }
    };

    load_group(0);

    for (int g = 0; g < NGROUP; ++g) {
        // stage group g (loads issued a full compute phase ago)
#pragma unroll
        for (int k = 0; k < 4; ++k) {
            int s = tid + k * 256;
            if (s < NSLOT) ((f4*)tile)[s] = P[k];
        }
        float sc[G][2];
#pragma unroll
        for (int ch = 0; ch < G; ++ch) { sc[ch][0] = S[ch][0]; sc[ch][1] = S[ch][1]; }
        __syncthreads();

        // issue next group's loads; they have the whole 4-channel compute
        // phase (~500+ cyc) before the next barrier's vmcnt(0) drain
        if (g + 1 < NGROUP) load_group(g + 1);

        // compute 4 channels: all ds_read_b32 w/ immediate offsets, conflict-free
#pragma unroll
        for (int ch = 0; ch < G; ++ch) {
            float v[10];  // column (4+x), rows 2ty .. 2ty+9
#pragma unroll
            for (int k = 0; k < 10; ++k) v[k] = tile[ch][2 * ty + k][RR + x];
#pragma unroll
            for (int i = 0; i < 2; ++i) {
                const float sv = sc[ch][i];
                acc[i][0] = fmaf(sv, v[4 + i], acc[i][0]);
#pragma unroll
                for (int off = 1; off <= RR; ++off) {
                    acc[i][4 * off - 3] = fmaf(sv, v[4 + i - off], acc[i][4 * off - 3]);  // up
                    acc[i][4 * off - 2] = fmaf(sv, v[4 + i + off], acc[i][4 * off - 2]);  // down
                }
            }
#pragma unroll
            for (int i = 0; i < 2; ++i) {
                const float sv = sc[ch][i];
                const float* row = &tile[ch][RR + 2 * ty + i][RR + x];
#pragma unroll
                for (int off = 1; off <= RR; ++off) {
                    acc[i][4 * off - 1] = fmaf(sv, row[-off], acc[i][4 * off - 1]);  // left
                    acc[i][4 * off    ] = fmaf(sv, row[ off], acc[i][4 * off    ]);  // right
                }
            }
        }
        __syncthreads();
    }

    // epilogue: R1's proven pattern — lane-per-column scalar atomics
#pragma unroll
    for (int i = 0; i < 2; ++i) {
        const int h = h0 + 2 * ty + i;
#pragma unroll
        for (int s = 0; s < NS; ++s) {
            atomicAdd(out + (((size_t)(b * NS + s)) * HH + h) * WW + w0 + x, acc[i][s]);
        }
    }
}

extern "C" void kernel_launch(void* const* d_in, const int* in_sizes, int n_in,
                              void* d_out, int out_size, void* d_ws, size_t ws_size,
                              hipStream_t stream) {
    const float* src = (const float*)d_in[0];
    const float* tgt = (const float*)d_in[1];
    float* out = (float*)d_out;

    // out is poisoned 0xAA before every launch; we accumulate atomically -> zero it
    hipMemsetAsync(out, 0, (size_t)out_size * sizeof(float), stream);

    dim3 block(TW, 8, 1);                        // 256 threads, 4 waves
    dim3 grid(WW / TW, HH / THT, BB * NCHUNK);   // (5, 6, 16) = 480 blocks
    cost_volume_kernel<<<grid, block, 0, stream>>>(src, tgt, out);
}